// Round 8
// baseline (93.861 us; speedup 1.0000x reference)
//
#include <hip/hip_runtime.h>
#include <hip/hip_fp16.h>

#define BB 16
#define HH 512
#define WW 512
#define NVV 35709
#define NTT 70000
#define HWW (HH * WW)
#define NVTOT (BB * NVV)          // 571344, divisible by 4

// World model (R0-R7, verified passing):
//   proj_geo, texture, nbl, ori_img : float32
//   is_visible, tri_inds, pixel_valid : int32
//   OUTPUT: float32, concatenated [render BHW3 | real BHW3]
//
// ws layout:  Shaded shw[NVTOT]            (8 B/vertex: half4 {r,g,b,vis})
//             __half2 acc[nb*HW*2]         (8 B/pixel: (r,g),(b,w)) per pass
//
// R7 post-mortem: compose at 5.8 TB/s logical = mixed-stream roofline; splat
// was ~20-25us of random gathers. This round: dense shade precompute so the
// splat gates+fetches color with 3x8B gathers instead of 3 vis + 24 f32.

typedef float fvec4 __attribute__((ext_vector_type(4)));

struct Shaded { __half2 rg; __half2 bv; };   // (r,g), (b, vis)
struct H4 { __half2 a, b, c, d; };

__global__ __launch_bounds__(256) void zero_kernel(float4* __restrict__ p, long n4)
{
    long i = (long)blockIdx.x * blockDim.x + threadIdx.x;
    long stride = (long)gridDim.x * blockDim.x;
    float4 z = {0.f, 0.f, 0.f, 0.f};
    for (; i < n4; i += stride) p[i] = z;
}

// Dense, coalesced: 4 vertices/thread. shaded = tex*nbl (f32 mul, f16 round),
// vis stored as f16 1.0/0.0 in .w.
__global__ __launch_bounds__(256) void shade_kernel(
    const float4* __restrict__ tex4,
    const float4* __restrict__ nbl4,
    const int4* __restrict__ vis4,
    fvec4* __restrict__ shw4)
{
    int q = blockIdx.x * blockDim.x + threadIdx.x;
    if (q >= NVTOT / 4) return;
    float4 T0 = tex4[q * 3 + 0], T1 = tex4[q * 3 + 1], T2 = tex4[q * 3 + 2];
    float4 N0 = nbl4[q * 3 + 0], N1 = nbl4[q * 3 + 1], N2 = nbl4[q * 3 + 2];
    int4 V = vis4[q];

    __half2 h0 = __floats2half2_rn(T0.x * N0.x, T0.y * N0.y);
    __half2 h1 = __floats2half2_rn(T0.z * N0.z, V.x ? 1.f : 0.f);
    __half2 h2 = __floats2half2_rn(T0.w * N0.w, T1.x * N1.x);
    __half2 h3 = __floats2half2_rn(T1.y * N1.y, V.y ? 1.f : 0.f);
    __half2 h4 = __floats2half2_rn(T1.z * N1.z, T1.w * N1.w);
    __half2 h5 = __floats2half2_rn(T2.x * N2.x, V.z ? 1.f : 0.f);
    __half2 h6 = __floats2half2_rn(T2.y * N2.y, T2.z * N2.z);
    __half2 h7 = __floats2half2_rn(T2.w * N2.w, V.w ? 1.f : 0.f);

    H4 lo = {h0, h1, h2, h3};
    H4 hi = {h4, h5, h6, h7};
    shw4[q * 2 + 0] = __builtin_bit_cast(fvec4, lo);
    shw4[q * 2 + 1] = __builtin_bit_cast(fvec4, hi);
}

__device__ inline void pk_add(__half2* p, __half2 v)
{
    unsafeAtomicAdd(p, v);   // global_atomic_pk_add_f16 on gfx950
}

__global__ __launch_bounds__(256) void splat_kernel(
    const float* __restrict__ proj,
    const float2* __restrict__ shw,      // Shaded as float2 (8B loads)
    const int* __restrict__ tri,
    __half2* __restrict__ acc,
    int b0)
{
    int t = blockIdx.x * blockDim.x + threadIdx.x;
    if (t >= NTT) return;
    int bl = blockIdx.y;          // local batch index within this pass
    int b = b0 + bl;              // global batch

    int i0 = tri[t * 3 + 0];
    int i1 = tri[t * 3 + 1];
    int i2 = tri[t * 3 + 2];
    int base = b * NVV;

    // one 8B gather per vertex gives color AND visibility
    Shaded s0 = __builtin_bit_cast(Shaded, shw[base + i0]);
    Shaded s1 = __builtin_bit_cast(Shaded, shw[base + i1]);
    Shaded s2 = __builtin_bit_cast(Shaded, shw[base + i2]);

    // tri_w = min(vis): zero-weight triangles contribute nothing.
    if (__high2float(s0.bv) == 0.f || __high2float(s1.bv) == 0.f ||
        __high2float(s2.bv) == 0.f) return;

    long p0 = (long)(base + i0) * 3;
    long p1 = (long)(base + i1) * 3;
    long p2 = (long)(base + i2) * 3;

    float x0 = proj[p0 + 0], y0 = proj[p0 + 1];
    float x1 = proj[p1 + 0], y1 = proj[p1 + 1];
    float x2 = proj[p2 + 0], y2 = proj[p2 + 1];

    float fx = ((x0 + x1) + x2) / 3.0f;   // numpy f32 pairwise sum + true_divide
    float fy = ((y0 + y1) + y2) / 3.0f;

    int px = (int)rintf(fx);              // np.round = round-half-even
    int py = (int)rintf(fy);
    px = min(max(px, 0), WW - 1);
    py = min(max(py, 0), HH - 1);

    float c0r = __low2float(s0.rg), c0g = __high2float(s0.rg), c0b = __low2float(s0.bv);
    float c1r = __low2float(s1.rg), c1g = __high2float(s1.rg), c1b = __low2float(s1.bv);
    float c2r = __low2float(s2.rg), c2g = __high2float(s2.rg), c2b = __low2float(s2.bv);

    float cr = ((c0r + c1r) + c2r) / 3.0f;
    float cg = ((c0g + c1g) + c2g) / 3.0f;
    float cb = ((c0b + c1b) + c2b) / 3.0f;

    long lin = (long)bl * HWW + (long)py * WW + px;   // LOCAL accumulator index
    pk_add(&acc[lin * 2 + 0], __floats2half2_rn(cr, cg));
    pk_add(&acc[lin * 2 + 1], __floats2half2_rn(cb, 1.0f));
}

__device__ inline float2 unpack_h2(float w)
{
    __half2 h = __builtin_bit_cast(__half2, w);
    return make_float2(__low2float(h), __high2float(h));
}

// 4 pixels per thread, all loads/stores 16B vectors.
__global__ __launch_bounds__(256) void compose_kernel(
    const float4* __restrict__ accv,     // local (pass) accumulator as float4
    const float4* __restrict__ oriv,
    const int4* __restrict__ pvv,
    fvec4* __restrict__ outv,
    int b0, int nb)
{
    long q = (long)blockIdx.x * blockDim.x + threadIdx.x;   // local 4-pixel group
    long ngrp = (long)nb * (HWW / 4);
    if (q >= ngrp) return;
    long qg = (long)b0 * (HWW / 4) + q;                     // global group

    float4 A0 = accv[q * 2 + 0];   // pixels 0,1: (rg,bw),(rg,bw)
    float4 A1 = accv[q * 2 + 1];   // pixels 2,3
    int4 PV = pvv[qg];
    float4 O0 = oriv[qg * 3 + 0];
    float4 O1 = oriv[qg * 3 + 1];
    float4 O2 = oriv[qg * 3 + 2];

    float of[12] = {O0.x, O0.y, O0.z, O0.w, O1.x, O1.y, O1.z, O1.w,
                    O2.x, O2.y, O2.z, O2.w};
    float2 rg[4], bw[4];
    rg[0] = unpack_h2(A0.x); bw[0] = unpack_h2(A0.y);
    rg[1] = unpack_h2(A0.z); bw[1] = unpack_h2(A0.w);
    rg[2] = unpack_h2(A1.x); bw[2] = unpack_h2(A1.y);
    rg[3] = unpack_h2(A1.z); bw[3] = unpack_h2(A1.w);
    int pva[4] = {PV.x, PV.y, PV.z, PV.w};

    float rd[12], rl[12];
#pragma unroll
    for (int p = 0; p < 4; ++p) {
        float w = bw[p].y;
        bool pv = pva[p] > 0;
        bool cov = (w > 0.f) && pv;
        float dn = fmaxf(w, 1.f);
        rd[p * 3 + 0] = cov ? rg[p].x / dn : of[p * 3 + 0];
        rd[p * 3 + 1] = cov ? rg[p].y / dn : of[p * 3 + 1];
        rd[p * 3 + 2] = cov ? bw[p].x / dn : of[p * 3 + 2];
        rl[p * 3 + 0] = pv ? of[p * 3 + 0] : 0.f;
        rl[p * 3 + 1] = pv ? of[p * 3 + 1] : 0.f;
        rl[p * 3 + 2] = pv ? of[p * 3 + 2] : 0.f;
    }

    const long RO4 = (long)BB * HWW * 3 / 4;   // `real` offset in float4 units
    fvec4 R0 = {rd[0], rd[1], rd[2], rd[3]};
    fvec4 R1 = {rd[4], rd[5], rd[6], rd[7]};
    fvec4 R2 = {rd[8], rd[9], rd[10], rd[11]};
    fvec4 L0 = {rl[0], rl[1], rl[2], rl[3]};
    fvec4 L1 = {rl[4], rl[5], rl[6], rl[7]};
    fvec4 L2 = {rl[8], rl[9], rl[10], rl[11]};
    __builtin_nontemporal_store(R0, &outv[qg * 3 + 0]);
    __builtin_nontemporal_store(R1, &outv[qg * 3 + 1]);
    __builtin_nontemporal_store(R2, &outv[qg * 3 + 2]);
    __builtin_nontemporal_store(L0, &outv[RO4 + qg * 3 + 0]);
    __builtin_nontemporal_store(L1, &outv[RO4 + qg * 3 + 1]);
    __builtin_nontemporal_store(L2, &outv[RO4 + qg * 3 + 2]);
}

extern "C" void kernel_launch(void* const* d_in, const int* in_sizes, int n_in,
                              void* d_out, int out_size, void* d_ws, size_t ws_size,
                              hipStream_t stream) {
    const float* proj = (const float*)d_in[0];
    const float* tex  = (const float*)d_in[1];
    const float* nbl  = (const float*)d_in[2];
    const float* ori  = (const float*)d_in[3];
    const int* vis    = (const int*)d_in[4];
    const int* tri    = (const int*)d_in[5];
    const int* pvalid = (const int*)d_in[6];
    float* out        = (float*)d_out;

    const size_t SHBYTES = (size_t)NVTOT * 8;          // 4.57 MB, 16B-aligned
    float2* shw = (float2*)d_ws;
    char* accBase = (char*)d_ws + SHBYTES;

    // shade once (covers all batches)
    shade_kernel<<<(NVTOT / 4 + 255) / 256, 256, 0, stream>>>(
        (const float4*)tex, (const float4*)nbl, (const int4*)vis, (fvec4*)d_ws);

    // batches per pass bounded by remaining workspace: 8 B/pixel accumulator
    const size_t perBatchBytes = (size_t)HWW * 8;      // 2 MiB
    size_t remain = (ws_size > SHBYTES) ? ws_size - SHBYTES : 0;
    int nbMax = (int)(remain / perBatchBytes);
    if (nbMax < 1) nbMax = 1;
    if (nbMax > BB) nbMax = BB;

    for (int b0 = 0; b0 < BB; b0 += nbMax) {
        int nb = (BB - b0 < nbMax) ? (BB - b0) : nbMax;

        __half2* acc = (__half2*)accBase;              // nb*HW*2 half2

        long n4 = (long)nb * HWW / 2;                  // float4 count (8B/px)
        int zblocks = (int)((n4 + 255) / 256);
        if (zblocks > 4096) zblocks = 4096;
        zero_kernel<<<zblocks, 256, 0, stream>>>((float4*)accBase, n4);

        dim3 gs((NTT + 255) / 256, nb);
        splat_kernel<<<gs, 256, 0, stream>>>(proj, shw, tri, acc, b0);

        long ngrp = (long)nb * (HWW / 4);
        compose_kernel<<<(int)((ngrp + 255) / 256), 256, 0, stream>>>(
            (const float4*)accBase, (const float4*)ori, (const int4*)pvalid,
            (fvec4*)out, b0, nb);
    }
}